// Round 1
// 261.135 us; speedup vs baseline: 1.0403x; 1.0403x over previous
//
#include <hip/hip_runtime.h>

// ---------------------------------------------------------------------------
// GraphSAGE 2-layer, bf16 MFMA + fp8 gather features. Pipeline (6 launches):
//   (memset gcur)
//   prep_part:    [grid-partitioned] per-chunk LDS hist of dst>>6, ONE global
//                 atomicAdd per (chunk,bucket) reserves a range in the
//                 fixed-capacity bucket region (CAP=4096), LDS-cursor scatter
//                 of packed pairs. Also xb=bf16(x), xq=fp8(x), WT*=bf16(W^T).
//   bucket_scatter: 1 wg/bucket, pairs staged in LDS (single global read),
//                 node-count scan -> offs/degs/inv_deg/csr.
//   agg_fp8:      streaming mean-agg, 1 wave/node, half-wave/edge, 32-edge
//                 batches (16 outstanding gathers/lane — L3-latency bound)
//   gemm_l1:      hb = bf16(relu(mean1@Wl1 + xb@Wr1 + bl1))   (MFMA)
//   gemm_l2:      pbq = fp8(hb@Wl2);  d_out = hb@Wr2 + bl2    (dual-B MFMA)
//   agg_fp8:      d_out += mean(pbq)  [projection-first]
// NOTES:
//  - R4: LDS-accumulator agg 20x slower. Do not revisit.
//  - R9 counters: agg is L3-LATENCY bound (Little's law matches 2.5 TB/s
//    L2-miss at 8 outstanding) -> R10 doubled outstanding to 16.
//  - R11 (this round): exact bucket compaction (cntmat/colscan/bucket_scan)
//    replaced by fixed-capacity buckets + atomic range reservation. Edge
//    order within a node was ALREADY nondeterministic (LDS-atomic cursors),
//    so compaction bought nothing. 9 launches -> 6.
//  - gemm_l1: B staged per-mat (32 KB LDS) -> 4-5 blocks/CU instead of 2;
//    staging overlaps compute across blocks. gemm_l2 keeps 64 KB (A once).
//  - LDS rotation swizzle (elem' = (e + row*8) & 127): conflict-free frag
//    reads without padding; 64/32 KB exact.
// ---------------------------------------------------------------------------

#define IN_DIM 128
#define HID_DIM 256
#define OUT_DIM 128

#define EPB 8192   // edges per chunk
#define NBMAX 784  // max buckets (50000/64 -> 782)
#define BCAP 4096  // slots per bucket (expected max ~2300 for 1.6M/782)

typedef unsigned short u16;
typedef unsigned int u32;
typedef unsigned char u8;
typedef __attribute__((ext_vector_type(8))) short short8;   // 8 bf16 (4 VGPRs)
typedef __attribute__((ext_vector_type(4))) float float4v;  // 4 fp32 acc
typedef __attribute__((ext_vector_type(2))) float float2v;

#if defined(__has_builtin)
#if __has_builtin(__builtin_amdgcn_cvt_pk_f32_fp8) && \
    __has_builtin(__builtin_amdgcn_cvt_pk_fp8_f32)
#define HAVE_HW_FP8 1
#endif
#endif

static __device__ __forceinline__ u16 f2bf(float f) {
    u32 u = __builtin_bit_cast(u32, f);
    u = (u + 0x7fffu + ((u >> 16) & 1u)) >> 16;
    return (u16)u;
}
static __device__ __forceinline__ float bf2f(u32 lo16) {
    return __builtin_bit_cast(float, lo16 << 16);
}

#if !defined(HAVE_HW_FP8)
// manual OCP e4m3 decode (handles denormals; NaN not expected in data)
static __device__ __forceinline__ float fp8_dec1(u32 v) {
    u32 s = (v & 0x80u) << 24;
    u32 e = (v >> 3) & 0xFu;
    u32 m = v & 7u;
    float mag = e ? __builtin_bit_cast(float, ((e + 120u) << 23) | (m << 20))
                  : (float)m * 0x1p-9f;
    return __builtin_bit_cast(float, __builtin_bit_cast(u32, mag) | s);
}
// manual OCP e4m3 encode, RNE, saturate to +-448
static __device__ __forceinline__ u32 fp8_enc1(float f) {
    u32 u = __builtin_bit_cast(u32, f);
    u32 s = (u >> 24) & 0x80u;
    float af = fabsf(f);
    if (af > 448.f) af = 448.f;
    u32 a = __builtin_bit_cast(u32, af);
    int e = (int)((a >> 23) & 0xFF) - 127;
    u32 q;
    if (af < 0x1p-10f) q = 0;
    else if (e < -6) {
        q = (u32)__builtin_rintf(af * 512.f);
    } else {
        u32 m = a & 0x7FFFFFu;
        u32 r = m >> 20;
        u32 rem = m & 0xFFFFFu;
        if (rem > 0x80000u || (rem == 0x80000u && (r & 1u))) r++;
        u32 ee = (u32)(e + 7);
        if (r == 8u) { r = 0; ee++; }
        if (ee >= 16u) { ee = 15u; r = 6u; }
        q = (ee << 3) | r;
    }
    return s | q;
}
#endif

// decode 2 fp8 (low or high 16 bits of dword) -> 2 f32.  HI is an immediate.
template <bool HI>
static __device__ __forceinline__ float2v fp8pk2f(u32 w) {
#if defined(HAVE_HW_FP8)
    return __builtin_amdgcn_cvt_pk_f32_fp8(w, HI);
#else
    float2v r;
    u32 b0 = HI ? ((w >> 16) & 0xFFu) : (w & 0xFFu);
    u32 b1 = HI ? (w >> 24) : ((w >> 8) & 0xFFu);
    r.x = fp8_dec1(b0);
    r.y = fp8_dec1(b1);
    return r;
#endif
}
// pack 2 f32 -> 2 fp8 into selected 16-bit word of old.  HI is an immediate.
template <bool HI>
static __device__ __forceinline__ u32 f2fp8pk(float a, float b, u32 old) {
#if defined(HAVE_HW_FP8)
    return (u32)__builtin_amdgcn_cvt_pk_fp8_f32(a, b, (int)old, HI);
#else
    u32 pk = fp8_enc1(a) | (fp8_enc1(b) << 8);
    return HI ? ((old & 0x0000FFFFu) | (pk << 16))
              : ((old & 0xFFFF0000u) | pk);
#endif
}
static __device__ __forceinline__ u8 f2fp8_1(float v) {
    return (u8)(f2fp8pk<false>(v, v, 0u) & 0xFFu);
}

// ---------- fused hist+reserve+partition + casts (grid-partitioned) --------
// chunk blocks: LDS hist of dst>>6 over EPB edges, one global atomicAdd per
// non-empty bucket reserves [i*BCAP + off, ...), LDS-atomic scatter of
// ((d&63)<<16 | src) pairs into the reserved range. No cntmat, no scans.

__global__ __launch_bounds__(256) void prep_part(
    const int* __restrict__ src, const int* __restrict__ dst, int n_edges,
    int nb, int nchunk, int* __restrict__ gcur, u32* __restrict__ pairs,
    const float* __restrict__ x, u16* __restrict__ xb, u32* __restrict__ xq,
    const float* __restrict__ Wl1, const float* __restrict__ Wr1,
    const float* __restrict__ Wl2, const float* __restrict__ Wr2,
    u16* __restrict__ WTl1, u16* __restrict__ WTr1,
    u16* __restrict__ WTl2, u16* __restrict__ WTr2, int n4, int xblocks) {
    __shared__ int h[NBMAX];
    __shared__ int curs[NBMAX];
    int b = blockIdx.x;
    int t = threadIdx.x;
    if (b < nchunk) {
        for (int i = t; i < nb; i += 256) h[i] = 0;
        __syncthreads();
        int base = b * EPB;
        int end = min(base + EPB, n_edges);
        for (int i = base + t; i < end; i += 256) atomicAdd(&h[dst[i] >> 6], 1);
        __syncthreads();
        for (int i = t; i < nb; i += 256) {
            int c = h[i];
            curs[i] = (c > 0) ? (i * BCAP + atomicAdd(&gcur[i], c)) : 0;
        }
        __syncthreads();
        for (int i = base + t; i < end; i += 256) {
            int d = dst[i];
            int pos = atomicAdd(&curs[d >> 6], 1);  // LDS atomic
            pairs[pos] = ((u32)(d & 63) << 16) | (u32)src[i];
        }
        return;
    }
    if (b < nchunk + xblocks) {
        int i = (b - nchunk) * 256 + t;
        if (i < n4) {
            float4 v = *(const float4*)(x + (size_t)i * 4);
            uint2 o;
            o.x = (u32)f2bf(v.x) | ((u32)f2bf(v.y) << 16);
            o.y = (u32)f2bf(v.z) | ((u32)f2bf(v.w) << 16);
            *(uint2*)(xb + (size_t)i * 4) = o;
            u32 q = f2fp8pk<false>(v.x, v.y, 0u);
            q = f2fp8pk<true>(v.z, v.w, q);
            xq[i] = q;
        }
        return;
    }
    int j = (b - nchunk - xblocks) * 256 + t;
    if (j >= 4 * 32768) return;
    int seg = j >> 15;
    int r = j & 32767;
    // seg 0/1: W [128][256] -> WT [256][128]; seg 2/3: W [256][128] -> WT [128][256]
    if (seg == 0) WTl1[r] = f2bf(Wl1[(size_t)(r & 127) * 256 + (r >> 7)]);
    else if (seg == 1) WTr1[r] = f2bf(Wr1[(size_t)(r & 127) * 256 + (r >> 7)]);
    else if (seg == 2) WTl2[r] = f2bf(Wl2[(size_t)(r & 255) * 128 + (r >> 8)]);
    else WTr2[r] = f2bf(Wr2[(size_t)(r & 255) * 128 + (r >> 8)]);
}

// ---------------- per-bucket CSR build (pairs staged in LDS) ---------------

__global__ __launch_bounds__(256) void bucket_scatter(
    const u32* __restrict__ pairs, const int* __restrict__ gcur,
    int n_nodes,
    int* __restrict__ offs, int* __restrict__ degs,
    float* __restrict__ inv_deg, int* __restrict__ csr) {
    int b = blockIdx.x;
    int t = threadIdx.x;
    int beg = b * BCAP;
    int cnt_b = gcur[b];
    if (cnt_b > BCAP) cnt_b = BCAP;  // safety only; never expected
    int end = beg + cnt_b;
    __shared__ u32 pbuf[BCAP];  // 16 KB
    __shared__ int cnt[64];
    __shared__ int cur[64];
    if (t < 64) cnt[t] = 0;
    __syncthreads();
    for (int i = beg + t; i < end; i += 256) {
        u32 pr = pairs[i];
        pbuf[i - beg] = pr;
        atomicAdd(&cnt[(pr >> 16) & 63], 1);
    }
    __syncthreads();
    if (t < 64) {  // wave 0: shuffle exclusive scan over 64 node counts
        int v = cnt[t];
        int incl = v;
#pragma unroll
        for (int off = 1; off < 64; off <<= 1) {
            int u = __shfl_up(incl, off, 64);
            if (t >= off) incl += u;
        }
        int o = beg + incl - v;
        int node = b * 64 + t;
        if (node < n_nodes) {
            offs[node] = o;
            degs[node] = v;
            inv_deg[node] = 1.0f / (float)(v > 0 ? v : 1);
        }
        cur[t] = o;
    }
    __syncthreads();
    for (int i = t; i < cnt_b; i += 256) {
        u32 pr = pbuf[i];
        int p = atomicAdd(&cur[(pr >> 16) & 63], 1);
        csr[p] = (int)(pr & 0xffffu);
    }
}

// -------------------- fp8 mean aggregation (1 wave/node) ------------------
// feat: fp8 rows, 32 dwords (=128 dims) per row. Half-wave per edge; 32-edge
// batches = 16 outstanding 128B gathers per lane (L3-latency bound: Little's
// law at 8 outstanding matched the observed 2.5 TB/s L2-miss rate).
// out_bf != 0: write bf16 mean.  else: out_f[row] += mean (in-place fp32).

__global__ __launch_bounds__(256) void agg_fp8(
    const u32* __restrict__ feat, const int* __restrict__ offs,
    const int* __restrict__ degs, const int* __restrict__ csr,
    const float* __restrict__ inv_deg, int n_nodes,
    u16* __restrict__ out_bf, float* __restrict__ out_f) {
    int wave = threadIdx.x >> 6;
    int lane = threadIdx.x & 63;
    int node = blockIdx.x * 4 + wave;
    if (node >= n_nodes) return;
    int beg = offs[node];
    int end = beg + degs[node];
    int half = lane >> 5, l32 = lane & 31;
    float a0 = 0.f, a1 = 0.f, a2 = 0.f, a3 = 0.f;
    int i = beg;
    for (; i + 32 <= end; i += 32) {  // 32 edges: 16 slots x 2 halves
        u32 w[16];
#pragma unroll
        for (int j = 0; j < 16; j++) {
            int s = csr[i + 2 * j + half];
            w[j] = feat[(size_t)s * 32 + l32];
        }
#pragma unroll
        for (int j = 0; j < 16; j++) {
            float2v lo = fp8pk2f<false>(w[j]);
            float2v hi = fp8pk2f<true>(w[j]);
            a0 += lo.x;
            a1 += lo.y;
            a2 += hi.x;
            a3 += hi.y;
        }
    }
    if (i + 16 <= end) {  // 16-edge remainder
        u32 w[8];
#pragma unroll
        for (int j = 0; j < 8; j++) {
            int s = csr[i + 2 * j + half];
            w[j] = feat[(size_t)s * 32 + l32];
        }
#pragma unroll
        for (int j = 0; j < 8; j++) {
            float2v lo = fp8pk2f<false>(w[j]);
            float2v hi = fp8pk2f<true>(w[j]);
            a0 += lo.x;
            a1 += lo.y;
            a2 += hi.x;
            a3 += hi.y;
        }
        i += 16;
    }
    if (i + 8 <= end) {  // 8-edge remainder
        u32 w[4];
#pragma unroll
        for (int j = 0; j < 4; j++) {
            int s = csr[i + 2 * j + half];
            w[j] = feat[(size_t)s * 32 + l32];
        }
#pragma unroll
        for (int j = 0; j < 4; j++) {
            float2v lo = fp8pk2f<false>(w[j]);
            float2v hi = fp8pk2f<true>(w[j]);
            a0 += lo.x;
            a1 += lo.y;
            a2 += hi.x;
            a3 += hi.y;
        }
        i += 8;
    }
    for (; i < end; i += 2) {  // tail: up to 2 edges per step
        bool on = (i + half) < end;
        u32 w = 0;
        if (on) {
            int s = csr[i + half];
            w = feat[(size_t)s * 32 + l32];
        }
        float2v lo = fp8pk2f<false>(w);
        float2v hi = fp8pk2f<true>(w);
        if (on) {
            a0 += lo.x;
            a1 += lo.y;
            a2 += hi.x;
            a3 += hi.y;
        }
    }
    // combine the two halves
    a0 += __shfl_xor(a0, 32);
    a1 += __shfl_xor(a1, 32);
    a2 += __shfl_xor(a2, 32);
    a3 += __shfl_xor(a3, 32);
    float inv = inv_deg[node];
    a0 *= inv;
    a1 *= inv;
    a2 *= inv;
    a3 *= inv;
    if (half == 0) {
        if (out_bf) {
            uint2 o;
            o.x = (u32)f2bf(a0) | ((u32)f2bf(a1) << 16);
            o.y = (u32)f2bf(a2) | ((u32)f2bf(a3) << 16);
            *(uint2*)(out_bf + (size_t)node * 128 + l32 * 4) = o;
        } else {
            float4* q = (float4*)(out_f + (size_t)node * 128 + l32 * 4);
            float4 o = *q;
            o.x += a0;
            o.y += a1;
            o.z += a2;
            o.w += a3;
            *q = o;
        }
    }
}

// -------------------- MFMA GEMMs --------------------
// Frag layouts (verified m89/m91): A[m=lane&15][k=quad*8+j] from row-major,
// B-frags from B^T rows, C/D: col=lane&15, row=quad*4+reg.
// 128-col strips; B^T panels LDS-resident with rotation swizzle:
// element e of row n stored at (e + n*8) & 127 — conflict-free frag reads.
// Block: 4 waves; wave = 32(M) x 128(N) via 2x8 of 16x16x32 mfma.

// layer 1: hb = bf16(relu(mean1@Wl1 + xb@Wr1 + bl1)), K=128, N=256.
// B staged per-mat (32 KB LDS) -> 4-5 blocks/CU; C = A1B1 + A2B2 accumulates
// across the two stages (no extra global traffic: A1,A2 distinct arrays).
__global__ __launch_bounds__(256) void gemm_l1(
    const u16* __restrict__ A1, const u16* __restrict__ A2,
    const u16* __restrict__ BT1, const u16* __restrict__ BT2,
    const float* __restrict__ bias, u16* __restrict__ out_bf, int M) {
    const int K = IN_DIM, N = HID_DIM;
    __shared__ u16 Bs[128 * 128];  // 32 KB, one mat at a time
    int t = threadIdx.x;
    int colbase = blockIdx.x * 128;
    int lane = t & 63, wave = t >> 6, quad = lane >> 4, l16 = lane & 15;
    int row_base = blockIdx.y * 128 + wave * 32;
    float4v zero = {0.f, 0.f, 0.f, 0.f};
    float4v acc[2][8];
#pragma unroll
    for (int mi = 0; mi < 2; mi++)
#pragma unroll
        for (int ni = 0; ni < 8; ni++) acc[mi][ni] = zero;

    for (int mat = 0; mat < 2; mat++) {
        if (mat) __syncthreads();  // waves done reading Bs
        const u16* BT = mat ? BT2 : BT1;
        for (int c = t; c < 2048; c += 256) {
            int n = c >> 4;          // panel row 0..127
            int e = (c & 15) * 8;    // element 0..120
            int es = (e + n * 8) & 127;
            *(uint4*)&Bs[n * 128 + es] =
                *(const uint4*)(BT + (size_t)(colbase + n) * K + e);
        }
        __syncthreads();
        const u16* A = mat ? A2 : A1;
#pragma unroll
        for (int ks = 0; ks < 4; ks++) {
            int k = ks * 32 + quad * 8;
            short8 af[2] = {{0, 0, 0, 0, 0, 0, 0, 0}, {0, 0, 0, 0, 0, 0, 0, 0}};
#pragma unroll
            for (int mi = 0; mi < 2; mi++) {
                int m = row_base + mi * 16 + l16;
                if (m < M) af[mi] = *(const short8*)(A + (size_t)m * K + k);
            }
#pragma unroll
            for (int ni = 0; ni < 8; ni++) {
                int nn = ni * 16 + l16;
                int es = (k + nn * 8) & 127;
                short8 bfr = *(const short8*)&Bs[nn * 128 + es];
                acc[0][ni] = __builtin_amdgcn_mfma_f32_16x16x32_bf16(
                    af[0], bfr, acc[0][ni], 0, 0, 0);
                acc[1][ni] = __builtin_amdgcn_mfma_f32_16x16x32_bf16(
                    af[1], bfr, acc[1][ni], 0, 0, 0);
            }
        }
    }
#pragma unroll
    for (int mi = 0; mi < 2; mi++)
#pragma unroll
        for (int r = 0; r < 4; r++) {
            int row = row_base + mi * 16 + quad * 4 + r;
            if (row >= M) continue;
#pragma unroll
            for (int ni = 0; ni < 8; ni++) {
                int col = colbase + ni * 16 + l16;
                float v = acc[mi][ni][r] + bias[col];
                v = fmaxf(v, 0.f);
                out_bf[(size_t)row * N + col] = f2bf(v);
            }
        }
}

// layer 2 dual-B: pbq = fp8(hb@Wl2); out = hb@Wr2 + bl2 (fp32). K=256, N=128
__global__ __launch_bounds__(256) void gemm_l2(
    const u16* __restrict__ A, const u16* __restrict__ BT1,
    const u16* __restrict__ BT2, const float* __restrict__ bias2,
    u8* __restrict__ out1_q, float* __restrict__ out2_f, int M) {
    const int K = HID_DIM, N = OUT_DIM;
    __shared__ u16 Bs[2][128 * 128];  // 64 KB, one 128-K chunk of each B
    int t = threadIdx.x;
    int lane = t & 63, wave = t >> 6, quad = lane >> 4, l16 = lane & 15;
    int row_base = blockIdx.y * 128 + wave * 32;
    float4v zero = {0.f, 0.f, 0.f, 0.f};
    float4v acc1[2][8], acc2[2][8];
#pragma unroll
    for (int mi = 0; mi < 2; mi++)
#pragma unroll
        for (int ni = 0; ni < 8; ni++) {
            acc1[mi][ni] = zero;
            acc2[mi][ni] = zero;
        }

    for (int kc = 0; kc < 2; kc++) {
        if (kc) __syncthreads();  // compute of previous chunk done
#pragma unroll
        for (int mat = 0; mat < 2; mat++) {
            const u16* BT = mat ? BT2 : BT1;
            for (int c = t; c < 2048; c += 256) {
                int n = c >> 4;
                int e = (c & 15) * 8;
                int es = (e + n * 8) & 127;
                *(uint4*)&Bs[mat][n * 128 + es] =
                    *(const uint4*)(BT + (size_t)n * K + kc * 128 + e);
            }
        }
        __syncthreads();
#pragma unroll
        for (int ks = 0; ks < 4; ks++) {
            int k = ks * 32 + quad * 8;
            int gk = kc * 128 + k;
            short8 af[2] = {{0, 0, 0, 0, 0, 0, 0, 0}, {0, 0, 0, 0, 0, 0, 0, 0}};
#pragma unroll
            for (int mi = 0; mi < 2; mi++) {
                int m = row_base + mi * 16 + l16;
                if (m < M) af[mi] = *(const short8*)(A + (size_t)m * K + gk);
            }
#pragma unroll
            for (int ni = 0; ni < 8; ni++) {
                int nn = ni * 16 + l16;
                int es = (k + nn * 8) & 127;
                short8 b1 = *(const short8*)&Bs[0][nn * 128 + es];
                short8 b2 = *(const short8*)&Bs[1][nn * 128 + es];
                acc1[0][ni] = __builtin_amdgcn_mfma_f32_16x16x32_bf16(
                    af[0], b1, acc1[0][ni], 0, 0, 0);
                acc1[1][ni] = __builtin_amdgcn_mfma_f32_16x16x32_bf16(
                    af[1], b1, acc1[1][ni], 0, 0, 0);
                acc2[0][ni] = __builtin_amdgcn_mfma_f32_16x16x32_bf16(
                    af[0], b2, acc2[0][ni], 0, 0, 0);
                acc2[1][ni] = __builtin_amdgcn_mfma_f32_16x16x32_bf16(
                    af[1], b2, acc2[1][ni], 0, 0, 0);
            }
        }
    }
#pragma unroll
    for (int mi = 0; mi < 2; mi++)
#pragma unroll
        for (int r = 0; r < 4; r++) {
            int row = row_base + mi * 16 + quad * 4 + r;
            if (row >= M) continue;
#pragma unroll
            for (int ni = 0; ni < 8; ni++) {
                int col = ni * 16 + l16;
                out1_q[(size_t)row * N + col] = f2fp8_1(acc1[mi][ni][r]);
                out2_f[(size_t)row * N + col] = acc2[mi][ni][r] + bias2[col];
            }
        }
}

// -------------------- launcher --------------------

extern "C" void kernel_launch(void* const* d_in, const int* in_sizes, int n_in,
                              void* d_out, int out_size, void* d_ws, size_t ws_size,
                              hipStream_t stream) {
    const float* x   = (const float*)d_in[0];
    const int*  eidx = (const int*)d_in[1];
    const float* Wl1 = (const float*)d_in[2];
    const float* bl1 = (const float*)d_in[3];
    const float* Wr1 = (const float*)d_in[4];
    const float* Wl2 = (const float*)d_in[5];
    const float* bl2 = (const float*)d_in[6];
    const float* Wr2 = (const float*)d_in[7];

    int n_nodes = in_sizes[0] / IN_DIM;
    int n_edges = in_sizes[1] / 2;
    const int* src = eidx;
    const int* dst = eidx + n_edges;
    int nb = (n_nodes + 63) / 64;            // buckets of 64 nodes
    int nchunk = (n_edges + EPB - 1) / EPB;  // edge chunks (196 <= 256)

    char* p = (char*)d_ws;
    auto alloc = [&](size_t bytes) {
        void* q = (void*)p;
        p += (bytes + 255) & ~(size_t)255;
        return q;
    };
    int*   gcur    = (int*)alloc((size_t)nb * 4);
    int*   offs    = (int*)alloc((size_t)n_nodes * 4);
    int*   degs    = (int*)alloc((size_t)n_nodes * 4);
    float* inv_deg = (float*)alloc((size_t)n_nodes * 4);
    u32*   pairs   = (u32*)alloc(((size_t)nb * BCAP + 8192) * 4);
    int*   csr     = (int*)alloc(((size_t)nb * BCAP + 8192) * 4);
    u16*   xb      = (u16*)alloc((size_t)n_nodes * IN_DIM * 2);
    u32*   xq      = (u32*)alloc((size_t)n_nodes * IN_DIM);      // fp8
    u16*   mean1b  = (u16*)alloc((size_t)n_nodes * IN_DIM * 2);
    u16*   hb      = (u16*)alloc((size_t)n_nodes * HID_DIM * 2);
    u8*    pbq     = (u8*)alloc((size_t)n_nodes * OUT_DIM);      // fp8
    u16*   WTl1b   = (u16*)alloc((size_t)IN_DIM * HID_DIM * 2);
    u16*   WTr1b   = (u16*)alloc((size_t)IN_DIM * HID_DIM * 2);
    u16*   WTl2b   = (u16*)alloc((size_t)HID_DIM * OUT_DIM * 2);
    u16*   WTr2b   = (u16*)alloc((size_t)HID_DIM * OUT_DIM * 2);

    int n4 = n_nodes * IN_DIM / 4;
    int xblocks = (n4 + 255) / 256;
    int wblocks = (4 * 32768 + 255) / 256;

    // bucket cursors start at 0 (offsets within fixed-capacity regions)
    hipMemsetAsync(gcur, 0, (size_t)nb * 4, stream);

    // fused hist + range-reservation + partition + casts
    prep_part<<<nchunk + xblocks + wblocks, 256, 0, stream>>>(
        src, dst, n_edges, nb, nchunk, gcur, pairs, x, xb, xq,
        Wl1, Wr1, Wl2, Wr2, WTl1b, WTr1b, WTl2b, WTr2b, n4, xblocks);

    // per-bucket CSR build (pairs staged in LDS, read once)
    bucket_scatter<<<nb, 256, 0, stream>>>(pairs, gcur, n_nodes, offs, degs,
                                           inv_deg, csr);

    int gx = (n_nodes + 127) / 128;

    // layer 1
    agg_fp8<<<(n_nodes + 3) / 4, 256, 0, stream>>>(xq, offs, degs, csr,
                                                   inv_deg, n_nodes, mean1b,
                                                   nullptr);
    {
        dim3 g(HID_DIM / 128, gx);
        gemm_l1<<<g, 256, 0, stream>>>(mean1b, xb, WTl1b, WTr1b, bl1, hb,
                                       n_nodes);
    }

    // layer 2: pbq = fp8(hb@Wl2) ; d_out = hb@Wr2 + bl2  (one pass over hb)
    {
        dim3 g(1, gx);
        gemm_l2<<<g, 256, 0, stream>>>(hb, WTl2b, WTr2b, bl2, pbq,
                                       (float*)d_out, n_nodes);
    }
    // d_out += mean(pbq)
    agg_fp8<<<(n_nodes + 3) / 4, 256, 0, stream>>>((const u32*)pbq, offs, degs,
                                                   csr, inv_deg, n_nodes,
                                                   nullptr, (float*)d_out);
}

// Round 2
// 242.421 us; speedup vs baseline: 1.1206x; 1.0772x over previous
//
#include <hip/hip_runtime.h>

// ---------------------------------------------------------------------------
// GraphSAGE 2-layer, bf16 MFMA + fp8 gather features. Pipeline (6 launches):
//   (memset gcur)
//   prep_part:    [grid-partitioned, 1024 thr] per-chunk LDS hist of dst>>6,
//                 ONE global atomicAdd per (chunk,bucket) reserves a range in
//                 the fixed-capacity bucket region (CAP=4096), LDS-cursor
//                 scatter of packed pairs. dst/src register-staged across the
//                 hist->scatter phases (single global read of each).
//                 Also xb=bf16(x), xq=fp8(x), WT*=bf16(W^T).
//   bucket_scatter: 1 wg/bucket (1024 thr), pairs staged in LDS (single
//                 global read), node-count scan -> offs/degs/inv_deg/csr.
//   agg_fp8:      streaming mean-agg, 1 wave/node, half-wave/edge, 32-edge
//                 batches (16 outstanding gathers/lane — L3-latency bound)
//   gemm_l1:      hb = bf16(relu(mean1@Wl1 + xb@Wr1 + bl1))   (MFMA)
//   gemm_l2:      pbq = fp8(hb@Wl2);  d_out = hb@Wr2 + bl2    (dual-B MFMA)
//   agg_fp8:      d_out += mean(pbq)  [projection-first]
// NOTES:
//  - R4: LDS-accumulator agg 20x slower. Do not revisit.
//  - R9 counters: agg is L3-LATENCY bound (Little's law matches 2.5 TB/s
//    L2-miss at 8 outstanding) -> R10 doubled outstanding to 16.
//  - R11: exact bucket compaction replaced by fixed-capacity buckets +
//    atomic range reservation; 9 launches -> 6 (271.7 -> 261.1 us).
//  - R12 counters: prep_part = 52-60 us, Occupancy 17%, VALUBusy 2.8%,
//    HBM 13% -> latency-bound at 4 waves/CU (196 blocks of 256 thr).
//    This round: 1024-thr chunk blocks (16 waves) + register-staged dst/src.
//  - gemm_l1: B staged per-mat (32 KB LDS) -> 4-5 blocks/CU instead of 2;
//    staging overlaps compute across blocks. gemm_l2 keeps 64 KB (A once).
//  - LDS rotation swizzle (elem' = (e + row*8) & 127): conflict-free frag
//    reads without padding; 64/32 KB exact.
// ---------------------------------------------------------------------------

#define IN_DIM 128
#define HID_DIM 256
#define OUT_DIM 128

#define EPB 8192   // edges per chunk
#define EPT 8      // edges per thread in chunk blocks (EPB/1024)
#define NBMAX 784  // max buckets (50000/64 -> 782)
#define BCAP 4096  // slots per bucket (expected max ~2300 for 1.6M/782)

typedef unsigned short u16;
typedef unsigned int u32;
typedef unsigned char u8;
typedef __attribute__((ext_vector_type(8))) short short8;   // 8 bf16 (4 VGPRs)
typedef __attribute__((ext_vector_type(4))) float float4v;  // 4 fp32 acc
typedef __attribute__((ext_vector_type(2))) float float2v;

#if defined(__has_builtin)
#if __has_builtin(__builtin_amdgcn_cvt_pk_f32_fp8) && \
    __has_builtin(__builtin_amdgcn_cvt_pk_fp8_f32)
#define HAVE_HW_FP8 1
#endif
#endif

static __device__ __forceinline__ u16 f2bf(float f) {
    u32 u = __builtin_bit_cast(u32, f);
    u = (u + 0x7fffu + ((u >> 16) & 1u)) >> 16;
    return (u16)u;
}
static __device__ __forceinline__ float bf2f(u32 lo16) {
    return __builtin_bit_cast(float, lo16 << 16);
}

#if !defined(HAVE_HW_FP8)
// manual OCP e4m3 decode (handles denormals; NaN not expected in data)
static __device__ __forceinline__ float fp8_dec1(u32 v) {
    u32 s = (v & 0x80u) << 24;
    u32 e = (v >> 3) & 0xFu;
    u32 m = v & 7u;
    float mag = e ? __builtin_bit_cast(float, ((e + 120u) << 23) | (m << 20))
                  : (float)m * 0x1p-9f;
    return __builtin_bit_cast(float, __builtin_bit_cast(u32, mag) | s);
}
// manual OCP e4m3 encode, RNE, saturate to +-448
static __device__ __forceinline__ u32 fp8_enc1(float f) {
    u32 u = __builtin_bit_cast(u32, f);
    u32 s = (u >> 24) & 0x80u;
    float af = fabsf(f);
    if (af > 448.f) af = 448.f;
    u32 a = __builtin_bit_cast(u32, af);
    int e = (int)((a >> 23) & 0xFF) - 127;
    u32 q;
    if (af < 0x1p-10f) q = 0;
    else if (e < -6) {
        q = (u32)__builtin_rintf(af * 512.f);
    } else {
        u32 m = a & 0x7FFFFFu;
        u32 r = m >> 20;
        u32 rem = m & 0xFFFFFu;
        if (rem > 0x80000u || (rem == 0x80000u && (r & 1u))) r++;
        u32 ee = (u32)(e + 7);
        if (r == 8u) { r = 0; ee++; }
        if (ee >= 16u) { ee = 15u; r = 6u; }
        q = (ee << 3) | r;
    }
    return s | q;
}
#endif

// decode 2 fp8 (low or high 16 bits of dword) -> 2 f32.  HI is an immediate.
template <bool HI>
static __device__ __forceinline__ float2v fp8pk2f(u32 w) {
#if defined(HAVE_HW_FP8)
    return __builtin_amdgcn_cvt_pk_f32_fp8(w, HI);
#else
    float2v r;
    u32 b0 = HI ? ((w >> 16) & 0xFFu) : (w & 0xFFu);
    u32 b1 = HI ? (w >> 24) : ((w >> 8) & 0xFFu);
    r.x = fp8_dec1(b0);
    r.y = fp8_dec1(b1);
    return r;
#endif
}
// pack 2 f32 -> 2 fp8 into selected 16-bit word of old.  HI is an immediate.
template <bool HI>
static __device__ __forceinline__ u32 f2fp8pk(float a, float b, u32 old) {
#if defined(HAVE_HW_FP8)
    return (u32)__builtin_amdgcn_cvt_pk_fp8_f32(a, b, (int)old, HI);
#else
    u32 pk = fp8_enc1(a) | (fp8_enc1(b) << 8);
    return HI ? ((old & 0x0000FFFFu) | (pk << 16))
              : ((old & 0xFFFF0000u) | pk);
#endif
}
static __device__ __forceinline__ u8 f2fp8_1(float v) {
    return (u8)(f2fp8pk<false>(v, v, 0u) & 0xFFu);
}

// ---------- fused hist+reserve+partition + casts (grid-partitioned) --------
// chunk blocks (16 waves): LDS hist of dst>>6 over EPB edges with dst/src
// register-staged, one global atomicAdd per non-empty bucket reserves
// [i*BCAP + off, ...), LDS-atomic scatter of ((d&63)<<16 | src) pairs.

__global__ __launch_bounds__(1024) void prep_part(
    const int* __restrict__ src, const int* __restrict__ dst, int n_edges,
    int nb, int nchunk, int* __restrict__ gcur, u32* __restrict__ pairs,
    const float* __restrict__ x, u16* __restrict__ xb, u32* __restrict__ xq,
    const float* __restrict__ Wl1, const float* __restrict__ Wr1,
    const float* __restrict__ Wl2, const float* __restrict__ Wr2,
    u16* __restrict__ WTl1, u16* __restrict__ WTr1,
    u16* __restrict__ WTl2, u16* __restrict__ WTr2, int n4, int xblocks) {
    __shared__ int h[NBMAX];
    __shared__ int curs[NBMAX];
    int b = blockIdx.x;
    int t = threadIdx.x;
    if (b < nchunk) {
        for (int i = t; i < nb; i += 1024) h[i] = 0;
        __syncthreads();
        int base = b * EPB;
        int dv[EPT], sv[EPT];
        bool on[EPT];
#pragma unroll
        for (int j = 0; j < EPT; j++) {
            int i = base + j * 1024 + t;
            on[j] = i < n_edges;
            if (on[j]) {
                dv[j] = dst[i];
                sv[j] = src[i];
                atomicAdd(&h[dv[j] >> 6], 1);
            }
        }
        __syncthreads();
        for (int i = t; i < nb; i += 1024) {
            int c = h[i];
            curs[i] = (c > 0) ? (i * BCAP + atomicAdd(&gcur[i], c)) : 0;
        }
        __syncthreads();
#pragma unroll
        for (int j = 0; j < EPT; j++) {
            if (on[j]) {
                int pos = atomicAdd(&curs[dv[j] >> 6], 1);  // LDS atomic
                pairs[pos] = ((u32)(dv[j] & 63) << 16) | (u32)sv[j];
            }
        }
        return;
    }
    if (b < nchunk + xblocks) {
        int i = (b - nchunk) * 1024 + t;
        if (i < n4) {
            float4 v = *(const float4*)(x + (size_t)i * 4);
            uint2 o;
            o.x = (u32)f2bf(v.x) | ((u32)f2bf(v.y) << 16);
            o.y = (u32)f2bf(v.z) | ((u32)f2bf(v.w) << 16);
            *(uint2*)(xb + (size_t)i * 4) = o;
            u32 q = f2fp8pk<false>(v.x, v.y, 0u);
            q = f2fp8pk<true>(v.z, v.w, q);
            xq[i] = q;
        }
        return;
    }
    int j = (b - nchunk - xblocks) * 1024 + t;
    if (j >= 4 * 32768) return;
    int seg = j >> 15;
    int r = j & 32767;
    // seg 0/1: W [128][256] -> WT [256][128]; seg 2/3: W [256][128] -> WT [128][256]
    if (seg == 0) WTl1[r] = f2bf(Wl1[(size_t)(r & 127) * 256 + (r >> 7)]);
    else if (seg == 1) WTr1[r] = f2bf(Wr1[(size_t)(r & 127) * 256 + (r >> 7)]);
    else if (seg == 2) WTl2[r] = f2bf(Wl2[(size_t)(r & 255) * 128 + (r >> 8)]);
    else WTr2[r] = f2bf(Wr2[(size_t)(r & 255) * 128 + (r >> 8)]);
}

// ---------------- per-bucket CSR build (pairs staged in LDS) ---------------

__global__ __launch_bounds__(1024) void bucket_scatter(
    const u32* __restrict__ pairs, const int* __restrict__ gcur,
    int n_nodes,
    int* __restrict__ offs, int* __restrict__ degs,
    float* __restrict__ inv_deg, int* __restrict__ csr) {
    int b = blockIdx.x;
    int t = threadIdx.x;
    int beg = b * BCAP;
    int cnt_b = gcur[b];
    if (cnt_b > BCAP) cnt_b = BCAP;  // safety only; never expected
    int end = beg + cnt_b;
    __shared__ u32 pbuf[BCAP];  // 16 KB
    __shared__ int cnt[64];
    __shared__ int cur[64];
    if (t < 64) cnt[t] = 0;
    __syncthreads();
    for (int i = beg + t; i < end; i += 1024) {
        u32 pr = pairs[i];
        pbuf[i - beg] = pr;
        atomicAdd(&cnt[(pr >> 16) & 63], 1);
    }
    __syncthreads();
    if (t < 64) {  // wave 0: shuffle exclusive scan over 64 node counts
        int v = cnt[t];
        int incl = v;
#pragma unroll
        for (int off = 1; off < 64; off <<= 1) {
            int u = __shfl_up(incl, off, 64);
            if (t >= off) incl += u;
        }
        int o = beg + incl - v;
        int node = b * 64 + t;
        if (node < n_nodes) {
            offs[node] = o;
            degs[node] = v;
            inv_deg[node] = 1.0f / (float)(v > 0 ? v : 1);
        }
        cur[t] = o;
    }
    __syncthreads();
    for (int i = t; i < cnt_b; i += 1024) {
        u32 pr = pbuf[i];
        int p = atomicAdd(&cur[(pr >> 16) & 63], 1);
        csr[p] = (int)(pr & 0xffffu);
    }
}

// -------------------- fp8 mean aggregation (1 wave/node) ------------------
// feat: fp8 rows, 32 dwords (=128 dims) per row. Half-wave per edge; 32-edge
// batches = 16 outstanding 128B gathers per lane (L3-latency bound: Little's
// law at 8 outstanding matched the observed 2.5 TB/s L2-miss rate).
// out_bf != 0: write bf16 mean.  else: out_f[row] += mean (in-place fp32).

__global__ __launch_bounds__(256) void agg_fp8(
    const u32* __restrict__ feat, const int* __restrict__ offs,
    const int* __restrict__ degs, const int* __restrict__ csr,
    const float* __restrict__ inv_deg, int n_nodes,
    u16* __restrict__ out_bf, float* __restrict__ out_f) {
    int wave = threadIdx.x >> 6;
    int lane = threadIdx.x & 63;
    int node = blockIdx.x * 4 + wave;
    if (node >= n_nodes) return;
    int beg = offs[node];
    int end = beg + degs[node];
    int half = lane >> 5, l32 = lane & 31;
    float a0 = 0.f, a1 = 0.f, a2 = 0.f, a3 = 0.f;
    int i = beg;
    for (; i + 32 <= end; i += 32) {  // 32 edges: 16 slots x 2 halves
        u32 w[16];
#pragma unroll
        for (int j = 0; j < 16; j++) {
            int s = csr[i + 2 * j + half];
            w[j] = feat[(size_t)s * 32 + l32];
        }
#pragma unroll
        for (int j = 0; j < 16; j++) {
            float2v lo = fp8pk2f<false>(w[j]);
            float2v hi = fp8pk2f<true>(w[j]);
            a0 += lo.x;
            a1 += lo.y;
            a2 += hi.x;
            a3 += hi.y;
        }
    }
    if (i + 16 <= end) {  // 16-edge remainder
        u32 w[8];
#pragma unroll
        for (int j = 0; j < 8; j++) {
            int s = csr[i + 2 * j + half];
            w[j] = feat[(size_t)s * 32 + l32];
        }
#pragma unroll
        for (int j = 0; j < 8; j++) {
            float2v lo = fp8pk2f<false>(w[j]);
            float2v hi = fp8pk2f<true>(w[j]);
            a0 += lo.x;
            a1 += lo.y;
            a2 += hi.x;
            a3 += hi.y;
        }
        i += 16;
    }
    if (i + 8 <= end) {  // 8-edge remainder
        u32 w[4];
#pragma unroll
        for (int j = 0; j < 4; j++) {
            int s = csr[i + 2 * j + half];
            w[j] = feat[(size_t)s * 32 + l32];
        }
#pragma unroll
        for (int j = 0; j < 4; j++) {
            float2v lo = fp8pk2f<false>(w[j]);
            float2v hi = fp8pk2f<true>(w[j]);
            a0 += lo.x;
            a1 += lo.y;
            a2 += hi.x;
            a3 += hi.y;
        }
        i += 8;
    }
    for (; i < end; i += 2) {  // tail: up to 2 edges per step
        bool on = (i + half) < end;
        u32 w = 0;
        if (on) {
            int s = csr[i + half];
            w = feat[(size_t)s * 32 + l32];
        }
        float2v lo = fp8pk2f<false>(w);
        float2v hi = fp8pk2f<true>(w);
        if (on) {
            a0 += lo.x;
            a1 += lo.y;
            a2 += hi.x;
            a3 += hi.y;
        }
    }
    // combine the two halves
    a0 += __shfl_xor(a0, 32);
    a1 += __shfl_xor(a1, 32);
    a2 += __shfl_xor(a2, 32);
    a3 += __shfl_xor(a3, 32);
    float inv = inv_deg[node];
    a0 *= inv;
    a1 *= inv;
    a2 *= inv;
    a3 *= inv;
    if (half == 0) {
        if (out_bf) {
            uint2 o;
            o.x = (u32)f2bf(a0) | ((u32)f2bf(a1) << 16);
            o.y = (u32)f2bf(a2) | ((u32)f2bf(a3) << 16);
            *(uint2*)(out_bf + (size_t)node * 128 + l32 * 4) = o;
        } else {
            float4* q = (float4*)(out_f + (size_t)node * 128 + l32 * 4);
            float4 o = *q;
            o.x += a0;
            o.y += a1;
            o.z += a2;
            o.w += a3;
            *q = o;
        }
    }
}

// -------------------- MFMA GEMMs --------------------
// Frag layouts (verified m89/m91): A[m=lane&15][k=quad*8+j] from row-major,
// B-frags from B^T rows, C/D: col=lane&15, row=quad*4+reg.
// 128-col strips; B^T panels LDS-resident with rotation swizzle:
// element e of row n stored at (e + n*8) & 127 — conflict-free frag reads.
// Block: 4 waves; wave = 32(M) x 128(N) via 2x8 of 16x16x32 mfma.

// layer 1: hb = bf16(relu(mean1@Wl1 + xb@Wr1 + bl1)), K=128, N=256.
// B staged per-mat (32 KB LDS) -> 4-5 blocks/CU; C = A1B1 + A2B2 accumulates
// across the two stages (no extra global traffic: A1,A2 distinct arrays).
__global__ __launch_bounds__(256) void gemm_l1(
    const u16* __restrict__ A1, const u16* __restrict__ A2,
    const u16* __restrict__ BT1, const u16* __restrict__ BT2,
    const float* __restrict__ bias, u16* __restrict__ out_bf, int M) {
    const int K = IN_DIM, N = HID_DIM;
    __shared__ u16 Bs[128 * 128];  // 32 KB, one mat at a time
    int t = threadIdx.x;
    int colbase = blockIdx.x * 128;
    int lane = t & 63, wave = t >> 6, quad = lane >> 4, l16 = lane & 15;
    int row_base = blockIdx.y * 128 + wave * 32;
    float4v zero = {0.f, 0.f, 0.f, 0.f};
    float4v acc[2][8];
#pragma unroll
    for (int mi = 0; mi < 2; mi++)
#pragma unroll
        for (int ni = 0; ni < 8; ni++) acc[mi][ni] = zero;

    for (int mat = 0; mat < 2; mat++) {
        if (mat) __syncthreads();  // waves done reading Bs
        const u16* BT = mat ? BT2 : BT1;
        for (int c = t; c < 2048; c += 256) {
            int n = c >> 4;          // panel row 0..127
            int e = (c & 15) * 8;    // element 0..120
            int es = (e + n * 8) & 127;
            *(uint4*)&Bs[n * 128 + es] =
                *(const uint4*)(BT + (size_t)(colbase + n) * K + e);
        }
        __syncthreads();
        const u16* A = mat ? A2 : A1;
#pragma unroll
        for (int ks = 0; ks < 4; ks++) {
            int k = ks * 32 + quad * 8;
            short8 af[2] = {{0, 0, 0, 0, 0, 0, 0, 0}, {0, 0, 0, 0, 0, 0, 0, 0}};
#pragma unroll
            for (int mi = 0; mi < 2; mi++) {
                int m = row_base + mi * 16 + l16;
                if (m < M) af[mi] = *(const short8*)(A + (size_t)m * K + k);
            }
#pragma unroll
            for (int ni = 0; ni < 8; ni++) {
                int nn = ni * 16 + l16;
                int es = (k + nn * 8) & 127;
                short8 bfr = *(const short8*)&Bs[nn * 128 + es];
                acc[0][ni] = __builtin_amdgcn_mfma_f32_16x16x32_bf16(
                    af[0], bfr, acc[0][ni], 0, 0, 0);
                acc[1][ni] = __builtin_amdgcn_mfma_f32_16x16x32_bf16(
                    af[1], bfr, acc[1][ni], 0, 0, 0);
            }
        }
    }
#pragma unroll
    for (int mi = 0; mi < 2; mi++)
#pragma unroll
        for (int r = 0; r < 4; r++) {
            int row = row_base + mi * 16 + quad * 4 + r;
            if (row >= M) continue;
#pragma unroll
            for (int ni = 0; ni < 8; ni++) {
                int col = colbase + ni * 16 + l16;
                float v = acc[mi][ni][r] + bias[col];
                v = fmaxf(v, 0.f);
                out_bf[(size_t)row * N + col] = f2bf(v);
            }
        }
}

// layer 2 dual-B: pbq = fp8(hb@Wl2); out = hb@Wr2 + bl2 (fp32). K=256, N=128
__global__ __launch_bounds__(256) void gemm_l2(
    const u16* __restrict__ A, const u16* __restrict__ BT1,
    const u16* __restrict__ BT2, const float* __restrict__ bias2,
    u8* __restrict__ out1_q, float* __restrict__ out2_f, int M) {
    const int K = HID_DIM, N = OUT_DIM;
    __shared__ u16 Bs[2][128 * 128];  // 64 KB, one 128-K chunk of each B
    int t = threadIdx.x;
    int lane = t & 63, wave = t >> 6, quad = lane >> 4, l16 = lane & 15;
    int row_base = blockIdx.y * 128 + wave * 32;
    float4v zero = {0.f, 0.f, 0.f, 0.f};
    float4v acc1[2][8], acc2[2][8];
#pragma unroll
    for (int mi = 0; mi < 2; mi++)
#pragma unroll
        for (int ni = 0; ni < 8; ni++) {
            acc1[mi][ni] = zero;
            acc2[mi][ni] = zero;
        }

    for (int kc = 0; kc < 2; kc++) {
        if (kc) __syncthreads();  // compute of previous chunk done
#pragma unroll
        for (int mat = 0; mat < 2; mat++) {
            const u16* BT = mat ? BT2 : BT1;
            for (int c = t; c < 2048; c += 256) {
                int n = c >> 4;
                int e = (c & 15) * 8;
                int es = (e + n * 8) & 127;
                *(uint4*)&Bs[mat][n * 128 + es] =
                    *(const uint4*)(BT + (size_t)n * K + kc * 128 + e);
            }
        }
        __syncthreads();
#pragma unroll
        for (int ks = 0; ks < 4; ks++) {
            int k = ks * 32 + quad * 8;
            int gk = kc * 128 + k;
            short8 af[2] = {{0, 0, 0, 0, 0, 0, 0, 0}, {0, 0, 0, 0, 0, 0, 0, 0}};
#pragma unroll
            for (int mi = 0; mi < 2; mi++) {
                int m = row_base + mi * 16 + l16;
                if (m < M) af[mi] = *(const short8*)(A + (size_t)m * K + gk);
            }
#pragma unroll
            for (int ni = 0; ni < 8; ni++) {
                int nn = ni * 16 + l16;
                int es = (k + nn * 8) & 127;
                short8 b1 = *(const short8*)&Bs[0][nn * 128 + es];
                short8 b2 = *(const short8*)&Bs[1][nn * 128 + es];
                acc1[0][ni] = __builtin_amdgcn_mfma_f32_16x16x32_bf16(
                    af[0], b1, acc1[0][ni], 0, 0, 0);
                acc1[1][ni] = __builtin_amdgcn_mfma_f32_16x16x32_bf16(
                    af[1], b1, acc1[1][ni], 0, 0, 0);
                acc2[0][ni] = __builtin_amdgcn_mfma_f32_16x16x32_bf16(
                    af[0], b2, acc2[0][ni], 0, 0, 0);
                acc2[1][ni] = __builtin_amdgcn_mfma_f32_16x16x32_bf16(
                    af[1], b2, acc2[1][ni], 0, 0, 0);
            }
        }
    }
#pragma unroll
    for (int mi = 0; mi < 2; mi++)
#pragma unroll
        for (int r = 0; r < 4; r++) {
            int row = row_base + mi * 16 + quad * 4 + r;
            if (row >= M) continue;
#pragma unroll
            for (int ni = 0; ni < 8; ni++) {
                int col = ni * 16 + l16;
                out1_q[(size_t)row * N + col] = f2fp8_1(acc1[mi][ni][r]);
                out2_f[(size_t)row * N + col] = acc2[mi][ni][r] + bias2[col];
            }
        }
}

// -------------------- launcher --------------------

extern "C" void kernel_launch(void* const* d_in, const int* in_sizes, int n_in,
                              void* d_out, int out_size, void* d_ws, size_t ws_size,
                              hipStream_t stream) {
    const float* x   = (const float*)d_in[0];
    const int*  eidx = (const int*)d_in[1];
    const float* Wl1 = (const float*)d_in[2];
    const float* bl1 = (const float*)d_in[3];
    const float* Wr1 = (const float*)d_in[4];
    const float* Wl2 = (const float*)d_in[5];
    const float* bl2 = (const float*)d_in[6];
    const float* Wr2 = (const float*)d_in[7];

    int n_nodes = in_sizes[0] / IN_DIM;
    int n_edges = in_sizes[1] / 2;
    const int* src = eidx;
    const int* dst = eidx + n_edges;
    int nb = (n_nodes + 63) / 64;            // buckets of 64 nodes
    int nchunk = (n_edges + EPB - 1) / EPB;  // edge chunks (196)

    char* p = (char*)d_ws;
    auto alloc = [&](size_t bytes) {
        void* q = (void*)p;
        p += (bytes + 255) & ~(size_t)255;
        return q;
    };
    int*   gcur    = (int*)alloc((size_t)nb * 4);
    int*   offs    = (int*)alloc((size_t)n_nodes * 4);
    int*   degs    = (int*)alloc((size_t)n_nodes * 4);
    float* inv_deg = (float*)alloc((size_t)n_nodes * 4);
    u32*   pairs   = (u32*)alloc(((size_t)nb * BCAP + 8192) * 4);
    int*   csr     = (int*)alloc(((size_t)nb * BCAP + 8192) * 4);
    u16*   xb      = (u16*)alloc((size_t)n_nodes * IN_DIM * 2);
    u32*   xq      = (u32*)alloc((size_t)n_nodes * IN_DIM);      // fp8
    u16*   mean1b  = (u16*)alloc((size_t)n_nodes * IN_DIM * 2);
    u16*   hb      = (u16*)alloc((size_t)n_nodes * HID_DIM * 2);
    u8*    pbq     = (u8*)alloc((size_t)n_nodes * OUT_DIM);      // fp8
    u16*   WTl1b   = (u16*)alloc((size_t)IN_DIM * HID_DIM * 2);
    u16*   WTr1b   = (u16*)alloc((size_t)IN_DIM * HID_DIM * 2);
    u16*   WTl2b   = (u16*)alloc((size_t)HID_DIM * OUT_DIM * 2);
    u16*   WTr2b   = (u16*)alloc((size_t)HID_DIM * OUT_DIM * 2);

    int n4 = n_nodes * IN_DIM / 4;
    int xblocks = (n4 + 1023) / 1024;
    int wblocks = (4 * 32768 + 1023) / 1024;

    // bucket cursors start at 0 (offsets within fixed-capacity regions)
    hipMemsetAsync(gcur, 0, (size_t)nb * 4, stream);

    // fused hist + range-reservation + partition + casts
    prep_part<<<nchunk + xblocks + wblocks, 1024, 0, stream>>>(
        src, dst, n_edges, nb, nchunk, gcur, pairs, x, xb, xq,
        Wl1, Wr1, Wl2, Wr2, WTl1b, WTr1b, WTl2b, WTr2b, n4, xblocks);

    // per-bucket CSR build (pairs staged in LDS, read once)
    bucket_scatter<<<nb, 1024, 0, stream>>>(pairs, gcur, n_nodes, offs, degs,
                                            inv_deg, csr);

    int gx = (n_nodes + 127) / 128;

    // layer 1
    agg_fp8<<<(n_nodes + 3) / 4, 256, 0, stream>>>(xq, offs, degs, csr,
                                                   inv_deg, n_nodes, mean1b,
                                                   nullptr);
    {
        dim3 g(HID_DIM / 128, gx);
        gemm_l1<<<g, 256, 0, stream>>>(mean1b, xb, WTl1b, WTr1b, bl1, hb,
                                       n_nodes);
    }

    // layer 2: pbq = fp8(hb@Wl2) ; d_out = hb@Wr2 + bl2  (one pass over hb)
    {
        dim3 g(1, gx);
        gemm_l2<<<g, 256, 0, stream>>>(hb, WTl2b, WTr2b, bl2, pbq,
                                       (float*)d_out, n_nodes);
    }
    // d_out += mean(pbq)
    agg_fp8<<<(n_nodes + 3) / 4, 256, 0, stream>>>((const u32*)pbq, offs, degs,
                                                   csr, inv_deg, n_nodes,
                                                   nullptr, (float*)d_out);
}

// Round 3
// 236.458 us; speedup vs baseline: 1.1489x; 1.0252x over previous
//
#include <hip/hip_runtime.h>

// ---------------------------------------------------------------------------
// GraphSAGE 2-layer, bf16 MFMA + fp8 gather features. Pipeline (5 launches):
//   (memset gcur)
//   prep_part:    [grid-partitioned, 1024 thr] per-chunk LDS hist of dst>>6,
//                 ONE global atomicAdd per (chunk,bucket) reserves a range in
//                 the fixed-capacity bucket region (CAP=4096), LDS-cursor
//                 scatter of packed pairs. dst/src register-staged.
//                 Also xb=bf16(x), xq=fp8(x), WT*=bf16(W^T).
//   bucket_agg:   FUSED CSR build + layer-1 mean-agg. 1 wg/bucket (16 waves):
//                 pairs -> LDS, per-node count/scan/scatter -> csr in LDS
//                 (u16, also written to global for layer 2), then each wave
//                 aggregates 4 nodes reading indices from LDS (no global csr
//                 round trip in the gather critical path).
//   gemm_l1:      hb = bf16(relu(mean1@Wl1 + xb@Wr1 + bl1))   (MFMA)
//   gemm_l2:      pbq = fp8(hb@Wl2);  d_out = hb@Wr2 + bl2    (dual-B MFMA)
//   agg_fp8:      d_out += mean(pbq)  [projection-first; u16 csr]
// NOTES:
//  - R4: LDS-accumulator agg 20x slower. Do not revisit.
//  - R9 counters: agg is L3-LATENCY bound (Little's law matches 2.5 TB/s
//    L2-miss at 8 outstanding) -> R10 doubled outstanding to 16. Gather
//    bytes are minimal (fp8, 128 B/row); ~62% L2 hit on 6.4 MB working set.
//  - R11: fixed-capacity buckets + atomic range reservation (9 -> 6 launches,
//    271.7 -> 261.1 us).
//  - R13: prep_part 256->1024 thr (latency-bound at 4 waves/CU, Occ 17%,
//    VALUBusy 2.8%) + register-staged dst/src: 261.1 -> 242.4 us.
//  - R14 (this round): bucket_scatter fused into layer-1 agg (bucket_agg);
//    csr stored as u16. 6 -> 5 kernels.
//  - gemm_l1: B staged per-mat (32 KB LDS) -> 4-5 blocks/CU instead of 2;
//    staging overlaps compute across blocks. gemm_l2 keeps 64 KB (A once).
//  - LDS rotation swizzle (elem' = (e + row*8) & 127): conflict-free frag
//    reads without padding; 64/32 KB exact.
// ---------------------------------------------------------------------------

#define IN_DIM 128
#define HID_DIM 256
#define OUT_DIM 128

#define EPB 8192   // edges per chunk
#define EPT 8      // edges per thread in chunk blocks (EPB/1024)
#define NBMAX 784  // max buckets (50000/64 -> 782)
#define BCAP 4096  // slots per bucket (expected max ~2300 for 1.6M/782)

typedef unsigned short u16;
typedef unsigned int u32;
typedef unsigned char u8;
typedef __attribute__((ext_vector_type(8))) short short8;   // 8 bf16 (4 VGPRs)
typedef __attribute__((ext_vector_type(4))) float float4v;  // 4 fp32 acc
typedef __attribute__((ext_vector_type(2))) float float2v;

#if defined(__has_builtin)
#if __has_builtin(__builtin_amdgcn_cvt_pk_f32_fp8) && \
    __has_builtin(__builtin_amdgcn_cvt_pk_fp8_f32)
#define HAVE_HW_FP8 1
#endif
#endif

static __device__ __forceinline__ u16 f2bf(float f) {
    u32 u = __builtin_bit_cast(u32, f);
    u = (u + 0x7fffu + ((u >> 16) & 1u)) >> 16;
    return (u16)u;
}
static __device__ __forceinline__ float bf2f(u32 lo16) {
    return __builtin_bit_cast(float, lo16 << 16);
}

#if !defined(HAVE_HW_FP8)
// manual OCP e4m3 decode (handles denormals; NaN not expected in data)
static __device__ __forceinline__ float fp8_dec1(u32 v) {
    u32 s = (v & 0x80u) << 24;
    u32 e = (v >> 3) & 0xFu;
    u32 m = v & 7u;
    float mag = e ? __builtin_bit_cast(float, ((e + 120u) << 23) | (m << 20))
                  : (float)m * 0x1p-9f;
    return __builtin_bit_cast(float, __builtin_bit_cast(u32, mag) | s);
}
// manual OCP e4m3 encode, RNE, saturate to +-448
static __device__ __forceinline__ u32 fp8_enc1(float f) {
    u32 u = __builtin_bit_cast(u32, f);
    u32 s = (u >> 24) & 0x80u;
    float af = fabsf(f);
    if (af > 448.f) af = 448.f;
    u32 a = __builtin_bit_cast(u32, af);
    int e = (int)((a >> 23) & 0xFF) - 127;
    u32 q;
    if (af < 0x1p-10f) q = 0;
    else if (e < -6) {
        q = (u32)__builtin_rintf(af * 512.f);
    } else {
        u32 m = a & 0x7FFFFFu;
        u32 r = m >> 20;
        u32 rem = m & 0xFFFFFu;
        if (rem > 0x80000u || (rem == 0x80000u && (r & 1u))) r++;
        u32 ee = (u32)(e + 7);
        if (r == 8u) { r = 0; ee++; }
        if (ee >= 16u) { ee = 15u; r = 6u; }
        q = (ee << 3) | r;
    }
    return s | q;
}
#endif

// decode 2 fp8 (low or high 16 bits of dword) -> 2 f32.  HI is an immediate.
template <bool HI>
static __device__ __forceinline__ float2v fp8pk2f(u32 w) {
#if defined(HAVE_HW_FP8)
    return __builtin_amdgcn_cvt_pk_f32_fp8(w, HI);
#else
    float2v r;
    u32 b0 = HI ? ((w >> 16) & 0xFFu) : (w & 0xFFu);
    u32 b1 = HI ? (w >> 24) : ((w >> 8) & 0xFFu);
    r.x = fp8_dec1(b0);
    r.y = fp8_dec1(b1);
    return r;
#endif
}
// pack 2 f32 -> 2 fp8 into selected 16-bit word of old.  HI is an immediate.
template <bool HI>
static __device__ __forceinline__ u32 f2fp8pk(float a, float b, u32 old) {
#if defined(HAVE_HW_FP8)
    return (u32)__builtin_amdgcn_cvt_pk_fp8_f32(a, b, (int)old, HI);
#else
    u32 pk = fp8_enc1(a) | (fp8_enc1(b) << 8);
    return HI ? ((old & 0x0000FFFFu) | (pk << 16))
              : ((old & 0xFFFF0000u) | pk);
#endif
}
static __device__ __forceinline__ u8 f2fp8_1(float v) {
    return (u8)(f2fp8pk<false>(v, v, 0u) & 0xFFu);
}

// ---------- fused hist+reserve+partition + casts (grid-partitioned) --------
// chunk blocks (16 waves): LDS hist of dst>>6 over EPB edges with dst/src
// register-staged, one global atomicAdd per non-empty bucket reserves
// [i*BCAP + off, ...), LDS-atomic scatter of ((d&63)<<16 | src) pairs.

__global__ __launch_bounds__(1024) void prep_part(
    const int* __restrict__ src, const int* __restrict__ dst, int n_edges,
    int nb, int nchunk, int* __restrict__ gcur, u32* __restrict__ pairs,
    const float* __restrict__ x, u16* __restrict__ xb, u32* __restrict__ xq,
    const float* __restrict__ Wl1, const float* __restrict__ Wr1,
    const float* __restrict__ Wl2, const float* __restrict__ Wr2,
    u16* __restrict__ WTl1, u16* __restrict__ WTr1,
    u16* __restrict__ WTl2, u16* __restrict__ WTr2, int n4, int xblocks) {
    __shared__ int h[NBMAX];
    __shared__ int curs[NBMAX];
    int b = blockIdx.x;
    int t = threadIdx.x;
    if (b < nchunk) {
        for (int i = t; i < nb; i += 1024) h[i] = 0;
        __syncthreads();
        int base = b * EPB;
        int dv[EPT], sv[EPT];
        bool on[EPT];
#pragma unroll
        for (int j = 0; j < EPT; j++) {
            int i = base + j * 1024 + t;
            on[j] = i < n_edges;
            if (on[j]) {
                dv[j] = dst[i];
                sv[j] = src[i];
                atomicAdd(&h[dv[j] >> 6], 1);
            }
        }
        __syncthreads();
        for (int i = t; i < nb; i += 1024) {
            int c = h[i];
            curs[i] = (c > 0) ? (i * BCAP + atomicAdd(&gcur[i], c)) : 0;
        }
        __syncthreads();
#pragma unroll
        for (int j = 0; j < EPT; j++) {
            if (on[j]) {
                int pos = atomicAdd(&curs[dv[j] >> 6], 1);  // LDS atomic
                pairs[pos] = ((u32)(dv[j] & 63) << 16) | (u32)sv[j];
            }
        }
        return;
    }
    if (b < nchunk + xblocks) {
        int i = (b - nchunk) * 1024 + t;
        if (i < n4) {
            float4 v = *(const float4*)(x + (size_t)i * 4);
            uint2 o;
            o.x = (u32)f2bf(v.x) | ((u32)f2bf(v.y) << 16);
            o.y = (u32)f2bf(v.z) | ((u32)f2bf(v.w) << 16);
            *(uint2*)(xb + (size_t)i * 4) = o;
            u32 q = f2fp8pk<false>(v.x, v.y, 0u);
            q = f2fp8pk<true>(v.z, v.w, q);
            xq[i] = q;
        }
        return;
    }
    int j = (b - nchunk - xblocks) * 1024 + t;
    if (j >= 4 * 32768) return;
    int seg = j >> 15;
    int r = j & 32767;
    // seg 0/1: W [128][256] -> WT [256][128]; seg 2/3: W [256][128] -> WT [128][256]
    if (seg == 0) WTl1[r] = f2bf(Wl1[(size_t)(r & 127) * 256 + (r >> 7)]);
    else if (seg == 1) WTr1[r] = f2bf(Wr1[(size_t)(r & 127) * 256 + (r >> 7)]);
    else if (seg == 2) WTl2[r] = f2bf(Wl2[(size_t)(r & 255) * 128 + (r >> 8)]);
    else WTr2[r] = f2bf(Wr2[(size_t)(r & 255) * 128 + (r >> 8)]);
}

// ------- FUSED per-bucket CSR build + layer-1 mean aggregation -------------
// 1 wg (16 waves) per bucket of 64 nodes. Phase 1: pairs -> LDS, per-node
// count, wave-0 scan, scatter to LDS csr (u16; also mirrored to global for
// the layer-2 agg). Phase 2: wave w aggregates nodes w*4..w*4+3, reading
// edge indices from LDS (no global csr in the gather critical path).

__global__ __launch_bounds__(1024) void bucket_agg(
    const u32* __restrict__ pairs, const int* __restrict__ gcur,
    const u32* __restrict__ feat, int n_nodes,
    int* __restrict__ offs, int* __restrict__ degs,
    float* __restrict__ inv_deg, u16* __restrict__ csr,
    u16* __restrict__ out_bf) {
    int b = blockIdx.x;
    int t = threadIdx.x;
    int beg = b * BCAP;
    int cnt_b = gcur[b];
    if (cnt_b > BCAP) cnt_b = BCAP;  // safety only; never expected
    __shared__ u32 pbuf[BCAP];  // 16 KB
    __shared__ u16 csrl[BCAP];  // 8 KB
    __shared__ int cnt[64];
    __shared__ int cur[64];
    __shared__ int soff[64];
    if (t < 64) cnt[t] = 0;
    __syncthreads();
    for (int i = t; i < cnt_b; i += 1024) {
        u32 pr = pairs[beg + i];
        pbuf[i] = pr;
        atomicAdd(&cnt[(pr >> 16) & 63], 1);
    }
    __syncthreads();
    if (t < 64) {  // wave 0: shuffle exclusive scan over 64 node counts
        int v = cnt[t];
        int incl = v;
#pragma unroll
        for (int off = 1; off < 64; off <<= 1) {
            int u = __shfl_up(incl, off, 64);
            if (t >= off) incl += u;
        }
        int o = incl - v;  // bucket-local exclusive offset
        soff[t] = o;
        cur[t] = o;
        int node = b * 64 + t;
        if (node < n_nodes) {
            offs[node] = beg + o;
            degs[node] = v;
            inv_deg[node] = 1.0f / (float)(v > 0 ? v : 1);
        }
    }
    __syncthreads();
    for (int i = t; i < cnt_b; i += 1024) {
        u32 pr = pbuf[i];
        int p = atomicAdd(&cur[(pr >> 16) & 63], 1);
        u16 s = (u16)(pr & 0xffffu);
        csrl[p] = s;
        csr[beg + p] = s;  // for layer-2 agg
    }
    __syncthreads();
    // ---- phase 2: aggregation, 4 nodes per wave, indices from LDS ----
    int wave = t >> 6, lane = t & 63;
    int half = lane >> 5, l32 = lane & 31;
#pragma unroll 1
    for (int q = 0; q < 4; q++) {
        int ln = wave * 4 + q;
        int node = b * 64 + ln;
        int s0 = soff[ln];
        int deg = cnt[ln];
        float a0 = 0.f, a1 = 0.f, a2 = 0.f, a3 = 0.f;
        int i = 0;
        for (; i + 32 <= deg; i += 32) {  // 32 edges: 16 slots x 2 halves
            u32 w[16];
#pragma unroll
            for (int j = 0; j < 16; j++) {
                int s = csrl[s0 + i + 2 * j + half];
                w[j] = feat[(size_t)s * 32 + l32];
            }
#pragma unroll
            for (int j = 0; j < 16; j++) {
                float2v lo = fp8pk2f<false>(w[j]);
                float2v hi = fp8pk2f<true>(w[j]);
                a0 += lo.x;
                a1 += lo.y;
                a2 += hi.x;
                a3 += hi.y;
            }
        }
        if (i + 16 <= deg) {
            u32 w[8];
#pragma unroll
            for (int j = 0; j < 8; j++) {
                int s = csrl[s0 + i + 2 * j + half];
                w[j] = feat[(size_t)s * 32 + l32];
            }
#pragma unroll
            for (int j = 0; j < 8; j++) {
                float2v lo = fp8pk2f<false>(w[j]);
                float2v hi = fp8pk2f<true>(w[j]);
                a0 += lo.x;
                a1 += lo.y;
                a2 += hi.x;
                a3 += hi.y;
            }
            i += 16;
        }
        if (i + 8 <= deg) {
            u32 w[4];
#pragma unroll
            for (int j = 0; j < 4; j++) {
                int s = csrl[s0 + i + 2 * j + half];
                w[j] = feat[(size_t)s * 32 + l32];
            }
#pragma unroll
            for (int j = 0; j < 4; j++) {
                float2v lo = fp8pk2f<false>(w[j]);
                float2v hi = fp8pk2f<true>(w[j]);
                a0 += lo.x;
                a1 += lo.y;
                a2 += hi.x;
                a3 += hi.y;
            }
            i += 8;
        }
        for (; i < deg; i += 2) {  // tail: up to 2 edges per step
            bool on = (i + half) < deg;
            u32 w = 0;
            if (on) {
                int s = csrl[s0 + i + half];
                w = feat[(size_t)s * 32 + l32];
            }
            float2v lo = fp8pk2f<false>(w);
            float2v hi = fp8pk2f<true>(w);
            if (on) {
                a0 += lo.x;
                a1 += lo.y;
                a2 += hi.x;
                a3 += hi.y;
            }
        }
        a0 += __shfl_xor(a0, 32);
        a1 += __shfl_xor(a1, 32);
        a2 += __shfl_xor(a2, 32);
        a3 += __shfl_xor(a3, 32);
        float inv = 1.0f / (float)(deg > 0 ? deg : 1);
        a0 *= inv;
        a1 *= inv;
        a2 *= inv;
        a3 *= inv;
        if (half == 0 && node < n_nodes) {
            uint2 o;
            o.x = (u32)f2bf(a0) | ((u32)f2bf(a1) << 16);
            o.y = (u32)f2bf(a2) | ((u32)f2bf(a3) << 16);
            *(uint2*)(out_bf + (size_t)node * 128 + l32 * 4) = o;
        }
    }
}

// -------------------- fp8 mean aggregation (1 wave/node) ------------------
// Layer-2 pass. feat: fp8 rows, 32 dwords (=128 dims) per row. Half-wave per
// edge; 32-edge batches = 16 outstanding 128B gathers per lane. csr is u16.
// out_f[row] += mean (in-place fp32).

__global__ __launch_bounds__(256) void agg_fp8(
    const u32* __restrict__ feat, const int* __restrict__ offs,
    const int* __restrict__ degs, const u16* __restrict__ csr,
    const float* __restrict__ inv_deg, int n_nodes,
    float* __restrict__ out_f) {
    int wave = threadIdx.x >> 6;
    int lane = threadIdx.x & 63;
    int node = blockIdx.x * 4 + wave;
    if (node >= n_nodes) return;
    int beg = offs[node];
    int end = beg + degs[node];
    int half = lane >> 5, l32 = lane & 31;
    float a0 = 0.f, a1 = 0.f, a2 = 0.f, a3 = 0.f;
    int i = beg;
    for (; i + 32 <= end; i += 32) {  // 32 edges: 16 slots x 2 halves
        u32 w[16];
#pragma unroll
        for (int j = 0; j < 16; j++) {
            int s = csr[i + 2 * j + half];
            w[j] = feat[(size_t)s * 32 + l32];
        }
#pragma unroll
        for (int j = 0; j < 16; j++) {
            float2v lo = fp8pk2f<false>(w[j]);
            float2v hi = fp8pk2f<true>(w[j]);
            a0 += lo.x;
            a1 += lo.y;
            a2 += hi.x;
            a3 += hi.y;
        }
    }
    if (i + 16 <= end) {  // 16-edge remainder
        u32 w[8];
#pragma unroll
        for (int j = 0; j < 8; j++) {
            int s = csr[i + 2 * j + half];
            w[j] = feat[(size_t)s * 32 + l32];
        }
#pragma unroll
        for (int j = 0; j < 8; j++) {
            float2v lo = fp8pk2f<false>(w[j]);
            float2v hi = fp8pk2f<true>(w[j]);
            a0 += lo.x;
            a1 += lo.y;
            a2 += hi.x;
            a3 += hi.y;
        }
        i += 16;
    }
    if (i + 8 <= end) {  // 8-edge remainder
        u32 w[4];
#pragma unroll
        for (int j = 0; j < 4; j++) {
            int s = csr[i + 2 * j + half];
            w[j] = feat[(size_t)s * 32 + l32];
        }
#pragma unroll
        for (int j = 0; j < 4; j++) {
            float2v lo = fp8pk2f<false>(w[j]);
            float2v hi = fp8pk2f<true>(w[j]);
            a0 += lo.x;
            a1 += lo.y;
            a2 += hi.x;
            a3 += hi.y;
        }
        i += 8;
    }
    for (; i < end; i += 2) {  // tail: up to 2 edges per step
        bool on = (i + half) < end;
        u32 w = 0;
        if (on) {
            int s = csr[i + half];
            w = feat[(size_t)s * 32 + l32];
        }
        float2v lo = fp8pk2f<false>(w);
        float2v hi = fp8pk2f<true>(w);
        if (on) {
            a0 += lo.x;
            a1 += lo.y;
            a2 += hi.x;
            a3 += hi.y;
        }
    }
    // combine the two halves
    a0 += __shfl_xor(a0, 32);
    a1 += __shfl_xor(a1, 32);
    a2 += __shfl_xor(a2, 32);
    a3 += __shfl_xor(a3, 32);
    float inv = inv_deg[node];
    a0 *= inv;
    a1 *= inv;
    a2 *= inv;
    a3 *= inv;
    if (half == 0) {
        float4* q = (float4*)(out_f + (size_t)node * 128 + l32 * 4);
        float4 o = *q;
        o.x += a0;
        o.y += a1;
        o.z += a2;
        o.w += a3;
        *q = o;
    }
}

// -------------------- MFMA GEMMs --------------------
// Frag layouts (verified m89/m91): A[m=lane&15][k=quad*8+j] from row-major,
// B-frags from B^T rows, C/D: col=lane&15, row=quad*4+reg.
// 128-col strips; B^T panels LDS-resident with rotation swizzle:
// element e of row n stored at (e + n*8) & 127 — conflict-free frag reads.
// Block: 4 waves; wave = 32(M) x 128(N) via 2x8 of 16x16x32 mfma.

// layer 1: hb = bf16(relu(mean1@Wl1 + xb@Wr1 + bl1)), K=128, N=256.
// B staged per-mat (32 KB LDS) -> 4-5 blocks/CU; C = A1B1 + A2B2 accumulates
// across the two stages (no extra global traffic: A1,A2 distinct arrays).
__global__ __launch_bounds__(256) void gemm_l1(
    const u16* __restrict__ A1, const u16* __restrict__ A2,
    const u16* __restrict__ BT1, const u16* __restrict__ BT2,
    const float* __restrict__ bias, u16* __restrict__ out_bf, int M) {
    const int K = IN_DIM, N = HID_DIM;
    __shared__ u16 Bs[128 * 128];  // 32 KB, one mat at a time
    int t = threadIdx.x;
    int colbase = blockIdx.x * 128;
    int lane = t & 63, wave = t >> 6, quad = lane >> 4, l16 = lane & 15;
    int row_base = blockIdx.y * 128 + wave * 32;
    float4v zero = {0.f, 0.f, 0.f, 0.f};
    float4v acc[2][8];
#pragma unroll
    for (int mi = 0; mi < 2; mi++)
#pragma unroll
        for (int ni = 0; ni < 8; ni++) acc[mi][ni] = zero;

    for (int mat = 0; mat < 2; mat++) {
        if (mat) __syncthreads();  // waves done reading Bs
        const u16* BT = mat ? BT2 : BT1;
        for (int c = t; c < 2048; c += 256) {
            int n = c >> 4;          // panel row 0..127
            int e = (c & 15) * 8;    // element 0..120
            int es = (e + n * 8) & 127;
            *(uint4*)&Bs[n * 128 + es] =
                *(const uint4*)(BT + (size_t)(colbase + n) * K + e);
        }
        __syncthreads();
        const u16* A = mat ? A2 : A1;
#pragma unroll
        for (int ks = 0; ks < 4; ks++) {
            int k = ks * 32 + quad * 8;
            short8 af[2] = {{0, 0, 0, 0, 0, 0, 0, 0}, {0, 0, 0, 0, 0, 0, 0, 0}};
#pragma unroll
            for (int mi = 0; mi < 2; mi++) {
                int m = row_base + mi * 16 + l16;
                if (m < M) af[mi] = *(const short8*)(A + (size_t)m * K + k);
            }
#pragma unroll
            for (int ni = 0; ni < 8; ni++) {
                int nn = ni * 16 + l16;
                int es = (k + nn * 8) & 127;
                short8 bfr = *(const short8*)&Bs[nn * 128 + es];
                acc[0][ni] = __builtin_amdgcn_mfma_f32_16x16x32_bf16(
                    af[0], bfr, acc[0][ni], 0, 0, 0);
                acc[1][ni] = __builtin_amdgcn_mfma_f32_16x16x32_bf16(
                    af[1], bfr, acc[1][ni], 0, 0, 0);
            }
        }
    }
#pragma unroll
    for (int mi = 0; mi < 2; mi++)
#pragma unroll
        for (int r = 0; r < 4; r++) {
            int row = row_base + mi * 16 + quad * 4 + r;
            if (row >= M) continue;
#pragma unroll
            for (int ni = 0; ni < 8; ni++) {
                int col = colbase + ni * 16 + l16;
                float v = acc[mi][ni][r] + bias[col];
                v = fmaxf(v, 0.f);
                out_bf[(size_t)row * N + col] = f2bf(v);
            }
        }
}

// layer 2 dual-B: pbq = fp8(hb@Wl2); out = hb@Wr2 + bl2 (fp32). K=256, N=128
__global__ __launch_bounds__(256) void gemm_l2(
    const u16* __restrict__ A, const u16* __restrict__ BT1,
    const u16* __restrict__ BT2, const float* __restrict__ bias2,
    u8* __restrict__ out1_q, float* __restrict__ out2_f, int M) {
    const int K = HID_DIM, N = OUT_DIM;
    __shared__ u16 Bs[2][128 * 128];  // 64 KB, one 128-K chunk of each B
    int t = threadIdx.x;
    int lane = t & 63, wave = t >> 6, quad = lane >> 4, l16 = lane & 15;
    int row_base = blockIdx.y * 128 + wave * 32;
    float4v zero = {0.f, 0.f, 0.f, 0.f};
    float4v acc1[2][8], acc2[2][8];
#pragma unroll
    for (int mi = 0; mi < 2; mi++)
#pragma unroll
        for (int ni = 0; ni < 8; ni++) {
            acc1[mi][ni] = zero;
            acc2[mi][ni] = zero;
        }

    for (int kc = 0; kc < 2; kc++) {
        if (kc) __syncthreads();  // compute of previous chunk done
#pragma unroll
        for (int mat = 0; mat < 2; mat++) {
            const u16* BT = mat ? BT2 : BT1;
            for (int c = t; c < 2048; c += 256) {
                int n = c >> 4;
                int e = (c & 15) * 8;
                int es = (e + n * 8) & 127;
                *(uint4*)&Bs[mat][n * 128 + es] =
                    *(const uint4*)(BT + (size_t)n * K + kc * 128 + e);
            }
        }
        __syncthreads();
#pragma unroll
        for (int ks = 0; ks < 4; ks++) {
            int k = ks * 32 + quad * 8;
            int gk = kc * 128 + k;
            short8 af[2] = {{0, 0, 0, 0, 0, 0, 0, 0}, {0, 0, 0, 0, 0, 0, 0, 0}};
#pragma unroll
            for (int mi = 0; mi < 2; mi++) {
                int m = row_base + mi * 16 + l16;
                if (m < M) af[mi] = *(const short8*)(A + (size_t)m * K + gk);
            }
#pragma unroll
            for (int ni = 0; ni < 8; ni++) {
                int nn = ni * 16 + l16;
                int es = (k + nn * 8) & 127;
                short8 b1 = *(const short8*)&Bs[0][nn * 128 + es];
                short8 b2 = *(const short8*)&Bs[1][nn * 128 + es];
                acc1[0][ni] = __builtin_amdgcn_mfma_f32_16x16x32_bf16(
                    af[0], b1, acc1[0][ni], 0, 0, 0);
                acc1[1][ni] = __builtin_amdgcn_mfma_f32_16x16x32_bf16(
                    af[1], b1, acc1[1][ni], 0, 0, 0);
                acc2[0][ni] = __builtin_amdgcn_mfma_f32_16x16x32_bf16(
                    af[0], b2, acc2[0][ni], 0, 0, 0);
                acc2[1][ni] = __builtin_amdgcn_mfma_f32_16x16x32_bf16(
                    af[1], b2, acc2[1][ni], 0, 0, 0);
            }
        }
    }
#pragma unroll
    for (int mi = 0; mi < 2; mi++)
#pragma unroll
        for (int r = 0; r < 4; r++) {
            int row = row_base + mi * 16 + quad * 4 + r;
            if (row >= M) continue;
#pragma unroll
            for (int ni = 0; ni < 8; ni++) {
                int col = ni * 16 + l16;
                out1_q[(size_t)row * N + col] = f2fp8_1(acc1[mi][ni][r]);
                out2_f[(size_t)row * N + col] = acc2[mi][ni][r] + bias2[col];
            }
        }
}

// -------------------- launcher --------------------

extern "C" void kernel_launch(void* const* d_in, const int* in_sizes, int n_in,
                              void* d_out, int out_size, void* d_ws, size_t ws_size,
                              hipStream_t stream) {
    const float* x   = (const float*)d_in[0];
    const int*  eidx = (const int*)d_in[1];
    const float* Wl1 = (const float*)d_in[2];
    const float* bl1 = (const float*)d_in[3];
    const float* Wr1 = (const float*)d_in[4];
    const float* Wl2 = (const float*)d_in[5];
    const float* bl2 = (const float*)d_in[6];
    const float* Wr2 = (const float*)d_in[7];

    int n_nodes = in_sizes[0] / IN_DIM;
    int n_edges = in_sizes[1] / 2;
    const int* src = eidx;
    const int* dst = eidx + n_edges;
    int nb = (n_nodes + 63) / 64;            // buckets of 64 nodes
    int nchunk = (n_edges + EPB - 1) / EPB;  // edge chunks (196)

    char* p = (char*)d_ws;
    auto alloc = [&](size_t bytes) {
        void* q = (void*)p;
        p += (bytes + 255) & ~(size_t)255;
        return q;
    };
    int*   gcur    = (int*)alloc((size_t)nb * 4);
    int*   offs    = (int*)alloc((size_t)n_nodes * 4);
    int*   degs    = (int*)alloc((size_t)n_nodes * 4);
    float* inv_deg = (float*)alloc((size_t)n_nodes * 4);
    u32*   pairs   = (u32*)alloc(((size_t)nb * BCAP + 8192) * 4);
    u16*   csr     = (u16*)alloc(((size_t)nb * BCAP + 8192) * 2);
    u16*   xb      = (u16*)alloc((size_t)n_nodes * IN_DIM * 2);
    u32*   xq      = (u32*)alloc((size_t)n_nodes * IN_DIM);      // fp8
    u16*   mean1b  = (u16*)alloc((size_t)n_nodes * IN_DIM * 2);
    u16*   hb      = (u16*)alloc((size_t)n_nodes * HID_DIM * 2);
    u8*    pbq     = (u8*)alloc((size_t)n_nodes * OUT_DIM);      // fp8
    u16*   WTl1b   = (u16*)alloc((size_t)IN_DIM * HID_DIM * 2);
    u16*   WTr1b   = (u16*)alloc((size_t)IN_DIM * HID_DIM * 2);
    u16*   WTl2b   = (u16*)alloc((size_t)HID_DIM * OUT_DIM * 2);
    u16*   WTr2b   = (u16*)alloc((size_t)HID_DIM * OUT_DIM * 2);

    int n4 = n_nodes * IN_DIM / 4;
    int xblocks = (n4 + 1023) / 1024;
    int wblocks = (4 * 32768 + 1023) / 1024;

    // bucket cursors start at 0 (offsets within fixed-capacity regions)
    hipMemsetAsync(gcur, 0, (size_t)nb * 4, stream);

    // fused hist + range-reservation + partition + casts
    prep_part<<<nchunk + xblocks + wblocks, 1024, 0, stream>>>(
        src, dst, n_edges, nb, nchunk, gcur, pairs, x, xb, xq,
        Wl1, Wr1, Wl2, Wr2, WTl1b, WTr1b, WTl2b, WTr2b, n4, xblocks);

    // fused CSR build + layer-1 mean aggregation
    bucket_agg<<<nb, 1024, 0, stream>>>(pairs, gcur, xq, n_nodes, offs, degs,
                                        inv_deg, csr, mean1b);

    int gx = (n_nodes + 127) / 128;

    // layer 1 GEMM
    {
        dim3 g(HID_DIM / 128, gx);
        gemm_l1<<<g, 256, 0, stream>>>(mean1b, xb, WTl1b, WTr1b, bl1, hb,
                                       n_nodes);
    }

    // layer 2: pbq = fp8(hb@Wl2) ; d_out = hb@Wr2 + bl2  (one pass over hb)
    {
        dim3 g(1, gx);
        gemm_l2<<<g, 256, 0, stream>>>(hb, WTl2b, WTr2b, bl2, pbq,
                                       (float*)d_out, n_nodes);
    }
    // d_out += mean(pbq)
    agg_fp8<<<(n_nodes + 3) / 4, 256, 0, stream>>>((const u32*)pbq, offs, degs,
                                                   csr, inv_deg, n_nodes,
                                                   (float*)d_out);
}